// Round 9
// baseline (695.125 us; speedup 1.0000x reference)
//
#include <hip/hip_runtime.h>
#include <hip/hip_fp16.h>
#include <math.h>

constexpr int BT = 65536;
constexpr int D  = 256;
constexpr int E  = 64;
constexpr int K  = 2048;
constexpr int J  = 512; // 2*D

// d_out layout (floats): res | topk_idx | topk_scores | counts
constexpr size_t OFF_IDX = (size_t)BT * D * 2;       // 33,554,432
constexpr size_t OFF_SCR = OFF_IDX + (size_t)E * K;  // +131,072
constexpr size_t OFF_CNT = OFF_SCR + (size_t)E * K;  // +131,072

// d_ws layout (bytes):
//   xb   bf16[BT][512]        @ 0          (64 MiB)
//   bm   bf16[E][512][512]    @ 64 MiB     (32 MiB)
//   yD   fp16[E*K][512]       @ 96 MiB     (128 MiB)   [tier-1 only]
//   cur  int[BT]              @ 224 MiB    (256 KiB)   [tier-1 only]
//   slot int[BT][32]          @ 224.25 MiB (8 MiB)     [tier-1 only]
constexpr size_t WS_XB    = 0;
constexpr size_t WS_BM    = 67108864;
constexpr size_t WS_YD    = 100663296;
constexpr size_t WS_CUR   = 234881024;
constexpr size_t WS_SLOT  = 235143168;
constexpr size_t WS_NEED1 = 243531776;              // tier-1: full path
constexpr size_t WS_NEED2 = 100663296;              // tier-2 path
constexpr int    SLOT_PAD = 32;

typedef __attribute__((ext_vector_type(8))) short bf16x8;
typedef __attribute__((ext_vector_type(4))) float f32x4;

__device__ __forceinline__ unsigned short f2bf(float f) {
  unsigned u = __float_as_uint(f);
  u = (u + 0x7FFFu + ((u >> 16) & 1u)) >> 16;  // RTNE
  return (unsigned short)u;
}

__device__ __forceinline__ void gl16(const void* g, void* l) {
  __builtin_amdgcn_global_load_lds(
      (const __attribute__((address_space(1))) unsigned int*)g,
      (__attribute__((address_space(3))) unsigned int*)l, 16, 0, 0);
}

__device__ __forceinline__ unsigned fkey(float s) {
  unsigned u = __float_as_uint(s);
  return (u & 0x80000000u) ? ~u : (u | 0x80000000u);
}

// ---------------------------------------------------------------------------
// K1: scoresT[e][t] = fp32 dot as ONE sequential FMA chain j=0..511
// (bit-matches the np reference's sgemm scheme — chain order DO NOT CHANGE).
// Fused: also emits xb = bf16(x) from the staged registers (xbp != null).
// ---------------------------------------------------------------------------
__global__ __launch_bounds__(256)
void k1_scores(const float* __restrict__ x, const float* __restrict__ gw,
               float* __restrict__ scoresT, unsigned short* __restrict__ xbp) {
  __shared__ float xs[64][65];
  __shared__ float gs[64][68];
  const int t0 = blockIdx.x * 64;
  const int tid = threadIdx.x;
  const int tx = tid & 15;
  const int ty = tid >> 4;
  float acc[4][4] = {};

#define K1_STAGE(kk)                                                        \
  for (int i = tid; i < 2048; i += 256) {                                   \
    int r = i >> 5, c2 = i & 31;                                            \
    float2 v = *(const float2*)(&x[(size_t)(t0 + r) * J + (kk) * 64 + c2*2]);\
    xs[r][c2 * 2] = v.x; xs[r][c2 * 2 + 1] = v.y;                           \
    if (xbp) {                                                              \
      unsigned u = (unsigned)f2bf(v.x) | ((unsigned)f2bf(v.y) << 16);       \
      *(unsigned*)(&xbp[(size_t)(t0 + r) * J + (kk) * 64 + c2 * 2]) = u;    \
    }                                                                       \
  }                                                                         \
  for (int i = tid; i < 4096; i += 256) {                                   \
    int r = i >> 6, c = i & 63;                                             \
    gs[r][c] = gw[(size_t)((kk) * 64 + r) * E + c];                         \
  }                                                                         \
  __syncthreads();

#define K1_INNER(ACC)                                                       \
  _Pragma("unroll 16")                                                      \
  for (int j = 0; j < 64; ++j) {                                            \
    float xv[4], gv[4];                                                     \
    _Pragma("unroll") for (int a = 0; a < 4; ++a) xv[a] = xs[a*16+tx][j];   \
    _Pragma("unroll") for (int b = 0; b < 4; ++b) gv[b] = gs[j][ty*4+b];    \
    _Pragma("unroll") for (int a = 0; a < 4; ++a)                           \
      _Pragma("unroll") for (int b = 0; b < 4; ++b)                         \
        ACC[a][b] = fmaf(xv[a], gv[b], ACC[a][b]);                          \
  }                                                                         \
  __syncthreads();

  for (int kk = 0; kk < 8; ++kk) { K1_STAGE(kk) K1_INNER(acc) }

#pragma unroll
  for (int b = 0; b < 4; ++b) {
    int e = ty * 4 + b;
#pragma unroll
    for (int a = 0; a < 4; ++a)
      scoresT[(size_t)e * BT + t0 + a * 16 + tx] = acc[a][b];
  }
}

// ---------------------------------------------------------------------------
// K2a: full-chip histogram of key top-16 bits. id = e*65536 + i.
// ---------------------------------------------------------------------------
__global__ __launch_bounds__(1024)
void k2a_hist(const float* __restrict__ scoresT, unsigned* __restrict__ h16) {
  const unsigned id = blockIdx.x * 1024 + threadIdx.x;
  unsigned u = fkey(scoresT[id]);
  atomicAdd(&h16[(id & 0xFFFF0000u) | (u >> 16)], 1u);
}

// ---------------------------------------------------------------------------
// K2b: per-expert descending scan of hist16 -> 16-bit bucket of rank-K key.
// ---------------------------------------------------------------------------
__global__ __launch_bounds__(256)
void k2b_scan(const unsigned* __restrict__ h16, unsigned* __restrict__ thr16) {
  const int e = blockIdx.x;
  const unsigned* h = h16 + ((size_t)e << 16);
  __shared__ unsigned chs[256];
  const int tid = threadIdx.x;
  const int base = (255 - tid) << 8;  // chunk `tid` = descending rank chunk
  unsigned s = 0;
  for (int j = 0; j < 256; j += 4) {
    uint4 v = *(const uint4*)(h + base + j);
    s += v.x + v.y + v.z + v.w;
  }
  chs[tid] = s;
  __syncthreads();
  if (tid == 0) {
    unsigned cum = 0; int c = 0;
    for (; c < 255; ++c) {
      if (cum + chs[c] >= (unsigned)K) break;
      cum += chs[c];
    }
    int vb = ((255 - c) << 8) + 255;  // highest value in chunk c
    unsigned b = 0;
    for (int j = 0; j < 256; ++j) {
      cum += h[vb - j];
      if (cum >= (unsigned)K) { b = (unsigned)(vb - j); break; }
    }
    thr16[e] = b;
  }
}

// ---------------------------------------------------------------------------
// K2c: collect candidates (u >= b<<16, a superset of top-K), bitonic sort
// (score desc, idx asc) — identical tail to verified k2 -> identical output.
// ---------------------------------------------------------------------------
__global__ __launch_bounds__(1024)
void k2c_collect(const float* __restrict__ scoresT,
                 const unsigned* __restrict__ thr16,
                 float* __restrict__ o_idx, float* __restrict__ o_scr,
                 float* __restrict__ o_cnt,
                 int* __restrict__ cur, int* __restrict__ slots) {
  const int e = blockIdx.x;
  const float* row = scoresT + ((size_t)e << 16);
  const unsigned bthr = thr16[e] << 16;
  __shared__ int sh_n;
  __shared__ unsigned long long keys[4096];
  const int tid = threadIdx.x;
  if (tid == 0) sh_n = 0;
  __syncthreads();
  for (int i = tid; i < BT; i += 1024) {
    unsigned u = fkey(row[i]);
    if (u >= bthr) {
      int pos = atomicAdd(&sh_n, 1);
      if (pos < 4096)
        keys[pos] = ((unsigned long long)u << 32) | (unsigned)(~(unsigned)i);
    }
  }
  __syncthreads();
  int n = sh_n; if (n > 4096) n = 4096;
  for (int i = n + tid; i < 4096; i += 1024) keys[i] = 0ull;
  __syncthreads();
  for (int kk = 2; kk <= 4096; kk <<= 1) {
    for (int j = kk >> 1; j > 0; j >>= 1) {
      for (int i = tid; i < 4096; i += 1024) {
        int ij = i ^ j;
        if (ij > i) {
          bool up = ((i & kk) == 0);
          unsigned long long a = keys[i], b = keys[ij];
          if ((a < b) == up) { keys[i] = b; keys[ij] = a; }
        }
      }
      __syncthreads();
    }
  }
  for (int r = tid; r < K; r += 1024) {
    unsigned long long kv = keys[r];
    unsigned u = (unsigned)(kv >> 32);
    unsigned idx = ~((unsigned)kv);
    float s = __uint_as_float((u & 0x80000000u) ? (u ^ 0x80000000u) : ~u);
    o_idx[(size_t)e * K + r] = (float)idx;
    o_scr[(size_t)e * K + r] = s;
    atomicAdd(&o_cnt[idx], 1.0f);
    if (slots) {
      int pos = atomicAdd(&cur[idx], 1);
      if (pos < SLOT_PAD) slots[(size_t)idx * SLOT_PAD + pos] = e * K + r;
    }
  }
}

// ---------------------------------------------------------------------------
// K3a (fallback only): xb[t][k] = bf16(x[t][k]).
// ---------------------------------------------------------------------------
__global__ __launch_bounds__(256)
void k3a_xbf(const float* __restrict__ x, unsigned short* __restrict__ xb) {
  int i = blockIdx.x * 256 + threadIdx.x;
  float4 v0 = ((const float4*)x)[i * 2];
  float4 v1 = ((const float4*)x)[i * 2 + 1];
  union { unsigned short h[8]; bf16x8 v; } pk;
  pk.h[0] = f2bf(v0.x); pk.h[1] = f2bf(v0.y);
  pk.h[2] = f2bf(v0.z); pk.h[3] = f2bf(v0.w);
  pk.h[4] = f2bf(v1.x); pk.h[5] = f2bf(v1.y);
  pk.h[6] = f2bf(v1.z); pk.h[7] = f2bf(v1.w);
  ((bf16x8*)xb)[i] = pk.v;
}

// ---------------------------------------------------------------------------
// K3b: Bmat[e][n=2f+co][k=2d+ci] = bf16( ew[e][d][f][ci^co] * sign ).
// ---------------------------------------------------------------------------
__global__ __launch_bounds__(256)
void k3b_bmat(const float* __restrict__ ew, unsigned short* __restrict__ bm) {
  int id = blockIdx.x * 256 + threadIdx.x;
  int sub = id & 63;
  int ng  = id >> 6;
  int e   = ng >> 9;
  int n   = ng & 511;
  int f   = n >> 1, co = n & 1;
  int d0  = sub * 4;
  const float* wb = ew + (((size_t)e * 256) * 256 + f) * 2;
  union { unsigned short h[8]; bf16x8 v; } pk;
#pragma unroll
  for (int dd = 0; dd < 4; ++dd) {
    float2 wv = *(const float2*)(wb + (size_t)(d0 + dd) * 512);
    float b0 = co ? wv.y : wv.x;
    float b1 = co ? wv.x : -wv.y;
    pk.h[dd * 2]     = f2bf(b0);
    pk.h[dd * 2 + 1] = f2bf(b1);
  }
  ((bf16x8*)bm)[id] = pk.v;
}

// ---------------------------------------------------------------------------
// K4c (tier-1): MFMA bf16 GEMM, dense fp16 output (NO atomics).
// 128x128 tile, BK=64, double-buffered LDS, XCD-local block mapping.
// ---------------------------------------------------------------------------
__global__ __launch_bounds__(256)
void k4c_mfma(const unsigned short* __restrict__ xb,
              const unsigned short* __restrict__ bm,
              const float* __restrict__ o_idx, const float* __restrict__ o_scr,
              unsigned short* __restrict__ yD) {
  const int bid = blockIdx.x;
  const int xcd = bid & 7;
  const int s   = bid >> 3;
  const int fn  = s & 3;
  const int km  = (s >> 2) & 15;
  const int e   = xcd + ((s >> 6) << 3);

  __shared__ __align__(16) unsigned short As[2 * 128 * 64];
  __shared__ __align__(16) unsigned short Bs[2 * 128 * 64];
  __shared__ int   tIdx[128];
  __shared__ float wRow[128];
  const int tid = threadIdx.x;
  if (tid < 128) {
    size_t gi = (size_t)e * K + km * 128 + tid;
    tIdx[tid] = (int)o_idx[gi];
    wRow[tid] = o_scr[gi];
  }
  __syncthreads();

  const int lane = tid & 63;
  const int w    = tid >> 6;
  const int wr   = (w & 1) * 64;
  const int wc   = (w >> 1) * 64;
  const int l15  = lane & 15, l4 = lane >> 4;
  const int ls   = lane & 7, lr = lane >> 3;
  const int gch  = ls ^ lr;  // pre-swizzled source chunk

  const char* aSrc[4];
  const char* bSrc[4];
  int dstOff[4];
#pragma unroll
  for (int i = 0; i < 4; ++i) {
    int r = w * 32 + i * 8 + lr;
    aSrc[i] = (const char*)xb + (size_t)tIdx[r] * 1024 + gch * 16;
    bSrc[i] = (const char*)bm + ((size_t)e * 512 + fn * 128 + r) * 1024 +
              gch * 16;
    dstOff[i] = (w * 32 + i * 8) * 64 + lane * 8;
  }

  f32x4 acc[4][4];
#pragma unroll
  for (int m = 0; m < 4; ++m)
#pragma unroll
    for (int n = 0; n < 4; ++n) acc[m][n] = (f32x4){0.f, 0.f, 0.f, 0.f};

#pragma unroll
  for (int i = 0; i < 4; ++i) {
    gl16(aSrc[i], As + dstOff[i]);
    gl16(bSrc[i], Bs + dstOff[i]);
  }

#pragma unroll
  for (int t = 0; t < 8; ++t) {
    const int cur = t & 1;
    __syncthreads();
    if (t < 7) {
      const int nxt = (cur ^ 1) * 8192;
#pragma unroll
      for (int i = 0; i < 4; ++i) {
        gl16(aSrc[i] + (t + 1) * 128, As + nxt + dstOff[i]);
        gl16(bSrc[i] + (t + 1) * 128, Bs + nxt + dstOff[i]);
      }
    }
    const unsigned short* Ab = As + cur * 8192;
    const unsigned short* Bb = Bs + cur * 8192;
#pragma unroll
    for (int kk2 = 0; kk2 < 2; ++kk2) {
      bf16x8 af[4], bfr[4];
#pragma unroll
      for (int m = 0; m < 4; ++m) {
        int r = wr + m * 16 + l15;
        int sw = (kk2 * 4 + l4) ^ (r & 7);
        af[m] = *(const bf16x8*)(&Ab[r * 64 + sw * 8]);
      }
#pragma unroll
      for (int n = 0; n < 4; ++n) {
        int cl = wc + n * 16 + l15;
        int sw = (kk2 * 4 + l4) ^ (cl & 7);
        bfr[n] = *(const bf16x8*)(&Bb[cl * 64 + sw * 8]);
      }
#pragma unroll
      for (int m = 0; m < 4; ++m)
#pragma unroll
        for (int n = 0; n < 4; ++n)
          acc[m][n] = __builtin_amdgcn_mfma_f32_16x16x32_bf16(
              af[m], bfr[n], acc[m][n], 0, 0, 0);
    }
  }

  __syncthreads();
  unsigned short* Pk = As;
#pragma unroll
  for (int m = 0; m < 4; ++m) {
#pragma unroll
    for (int q = 0; q < 4; ++q) {
      int row = wr + m * 16 + l4 * 4 + q;
      float wv = wRow[row];
#pragma unroll
      for (int n = 0; n < 4; ++n) {
        int col = wc + n * 16 + l15;
        Pk[row * 128 + col] =
            __half_as_ushort(__float2half(acc[m][n][q] * wv));
      }
    }
  }
  __syncthreads();
  const size_t rowBase = (size_t)e * K + km * 128;
#pragma unroll
  for (int i = 0; i < 8; ++i) {
    int c2 = tid + 256 * i;
    int row = c2 >> 4, ch = c2 & 15;
    uint4 v = *(const uint4*)(&Pk[row * 128 + ch * 8]);
    *(uint4*)(yD + (rowBase + row) * 512 + fn * 128 + ch * 8) = v;
  }
}

// ---------------------------------------------------------------------------
// K5g (tier-1): per-token gather-finalize (one wave per token).
// ---------------------------------------------------------------------------
__global__ __launch_bounds__(256)
void k5g(const unsigned short* __restrict__ yD, const int* __restrict__ cur,
         const int* __restrict__ slots, const float* __restrict__ bias,
         float* __restrict__ res) {
  const int t    = blockIdx.x * 4 + (threadIdx.x >> 6);
  const int lane = threadIdx.x & 63;
  const int nc   = cur[t];
  const int ncc  = nc < SLOT_PAD ? nc : SLOT_PAD;
  float acc[8] = {};
  const int* sl = slots + (size_t)t * SLOT_PAD;
  for (int c = 0; c < ncc; ++c) {
    int slot = sl[c];
    union { uint4 v; unsigned short h[8]; } U;
    U.v = *(const uint4*)(yD + (size_t)slot * 512 + lane * 8);
#pragma unroll
    for (int j = 0; j < 8; ++j)
      acc[j] += __half2float(__ushort_as_half(U.h[j]));
  }
  const float inv = 1.0f / fmaxf((float)nc, 1.0f);
  float4 b4 = *(const float4*)(bias + lane * 4);
  const float* bp = (const float*)&b4;
  const float is2 = 0.70710678118654752f;
  float r8[8];
#pragma unroll
  for (int j = 0; j < 8; ++j) {
    float h = acc[j] * inv + bp[j >> 1];
    r8[j] = 0.5f * h * (1.0f + erff(h * is2));
  }
  float* dst = res + (size_t)t * J + lane * 8;
  *(float4*)dst       = make_float4(r8[0], r8[1], r8[2], r8[3]);
  *(float4*)(dst + 4) = make_float4(r8[4], r8[5], r8[6], r8[7]);
}

// ---------------------------------------------------------------------------
// K4b (tier-2 fallback): atomic-scatter MFMA GEMM (round-7 verified).
// ---------------------------------------------------------------------------
__global__ __launch_bounds__(256)
void k4b_mfma(const unsigned short* __restrict__ xb,
              const unsigned short* __restrict__ bm,
              const float* __restrict__ o_idx, const float* __restrict__ o_scr,
              float* __restrict__ out) {
  const int e  = blockIdx.z;
  const int km = blockIdx.y;
  const int fn = blockIdx.x;
  __shared__ __align__(16) unsigned short As[128 * 64];
  __shared__ __align__(16) unsigned short Bs[128 * 64];
  __shared__ int   tIdx[128];
  __shared__ float wRow[128];
  const int tid = threadIdx.x;
  if (tid < 128) {
    size_t gi = (size_t)e * K + km * 128 + tid;
    tIdx[tid] = (int)o_idx[gi];
    wRow[tid] = o_scr[gi];
  }
  __syncthreads();

  const int lane = tid & 63;
  const int w    = tid >> 6;
  const int wr   = (w & 1) * 64;
  const int wc   = (w >> 1) * 64;
  const int l15  = lane & 15, l4 = lane >> 4;
  const int ls   = lane & 7, lr = lane >> 3;
  const int gch  = ls ^ lr;

  const char* aSrc[4];
  const char* bSrc[4];
  unsigned short* aDst[4];
  unsigned short* bDst[4];
#pragma unroll
  for (int i = 0; i < 4; ++i) {
    int r = w * 32 + i * 8 + lr;
    aSrc[i] = (const char*)xb + (size_t)tIdx[r] * 1024 + gch * 16;
    bSrc[i] = (const char*)bm + ((size_t)e * 512 + fn * 128 + r) * 1024 +
              gch * 16;
    aDst[i] = As + (w * 32 + i * 8) * 64 + lane * 8;
    bDst[i] = Bs + (w * 32 + i * 8) * 64 + lane * 8;
  }

  f32x4 acc[4][4];
#pragma unroll
  for (int m = 0; m < 4; ++m)
#pragma unroll
    for (int n = 0; n < 4; ++n) acc[m][n] = (f32x4){0.f, 0.f, 0.f, 0.f};

  for (int kk = 0; kk < J; kk += 64) {
#pragma unroll
    for (int i = 0; i < 4; ++i) {
      gl16(aSrc[i] + kk * 2, aDst[i]);
      gl16(bSrc[i] + kk * 2, bDst[i]);
    }
    __syncthreads();
#pragma unroll
    for (int kk2 = 0; kk2 < 2; ++kk2) {
      bf16x8 af[4], bfr[4];
#pragma unroll
      for (int m = 0; m < 4; ++m) {
        int r = wr + m * 16 + l15;
        int s = (kk2 * 4 + l4) ^ (r & 7);
        af[m] = *(const bf16x8*)(&As[r * 64 + s * 8]);
      }
#pragma unroll
      for (int n = 0; n < 4; ++n) {
        int cl = wc + n * 16 + l15;
        int s = (kk2 * 4 + l4) ^ (cl & 7);
        bfr[n] = *(const bf16x8*)(&Bs[cl * 64 + s * 8]);
      }
#pragma unroll
      for (int m = 0; m < 4; ++m)
#pragma unroll
        for (int n = 0; n < 4; ++n)
          acc[m][n] = __builtin_amdgcn_mfma_f32_16x16x32_bf16(
              af[m], bfr[n], acc[m][n], 0, 0, 0);
    }
    __syncthreads();
  }

#pragma unroll
  for (int m = 0; m < 4; ++m) {
#pragma unroll
    for (int q = 0; q < 4; ++q) {
      int rl = wr + m * 16 + l4 * 4 + q;
      int t = tIdx[rl];
      float wv = wRow[rl];
      float* dst = out + (size_t)t * J + fn * 128 + wc + l15;
#pragma unroll
      for (int n = 0; n < 4; ++n)
        atomicAdd(dst + n * 16, acc[m][n][q] * wv);
    }
  }
}

// ---------------------------------------------------------------------------
// K5 (tier-2 fallback): res = gelu(out/max(cnt,1)+bias), in place.
// ---------------------------------------------------------------------------
__global__ __launch_bounds__(256)
void k5_final(float* __restrict__ res, const float* __restrict__ cnt,
              const float* __restrict__ bias) {
  const int total4 = BT * J / 4;
  for (int i = blockIdx.x * blockDim.x + threadIdx.x; i < total4;
       i += gridDim.x * blockDim.x) {
    float4 v = reinterpret_cast<float4*>(res)[i];
    int base = i << 2;
    int t = base >> 9;
    int col = base & 511;
    float inv = 1.0f / fmaxf(cnt[t], 1.0f);
    int f0 = col >> 1;
    float b0 = bias[f0], b1 = bias[f0 + 1];
    float h0 = v.x * inv + b0;
    float h1 = v.y * inv + b0;
    float h2 = v.z * inv + b1;
    float h3 = v.w * inv + b1;
    const float is2 = 0.70710678118654752f;
    v.x = 0.5f * h0 * (1.0f + erff(h0 * is2));
    v.y = 0.5f * h1 * (1.0f + erff(h1 * is2));
    v.z = 0.5f * h2 * (1.0f + erff(h2 * is2));
    v.w = 0.5f * h3 * (1.0f + erff(h3 * is2));
    reinterpret_cast<float4*>(res)[i] = v;
  }
}

// ---------------------------------------------------------------------------
extern "C" void kernel_launch(void* const* d_in, const int* in_sizes, int n_in,
                              void* d_out, int out_size, void* d_ws,
                              size_t ws_size, hipStream_t stream) {
  const float* x    = (const float*)d_in[0];
  const float* gw   = (const float*)d_in[1];
  const float* ew   = (const float*)d_in[2];
  const float* bias = (const float*)d_in[3];

  float* out_f = (float*)d_out;
  float* res   = out_f;
  float* o_idx = out_f + OFF_IDX;
  float* o_scr = out_f + OFF_SCR;
  float* o_cnt = out_f + OFF_CNT;

  // Borrowed regions inside res (rewritten later by k5):
  //   scoresT: floats [0, 16.7MB); hist16: @ +32MB (16.7MB); thr16 after it.
  float*    scoresT = res;
  unsigned* hist16  = (unsigned*)(res + (size_t)8 * 1024 * 1024);
  unsigned* thr16   = hist16 + (size_t)E * 65536;

  unsigned short* xb  = (unsigned short*)((char*)d_ws + WS_XB);
  unsigned short* bm  = (unsigned short*)((char*)d_ws + WS_BM);
  unsigned short* yD  = (unsigned short*)((char*)d_ws + WS_YD);
  int*            cur = (int*)((char*)d_ws + WS_CUR);
  int*            slt = (int*)((char*)d_ws + WS_SLOT);

  const bool tier1 = (ws_size >= WS_NEED1);
  const bool tier2 = (ws_size >= WS_NEED2);

  if (tier2) k3b_bmat<<<8192, 256, 0, stream>>>(ew, bm);
  hipMemsetAsync(o_cnt, 0, (size_t)BT * sizeof(float), stream);
  hipMemsetAsync(hist16, 0, (size_t)E * 65536 * sizeof(unsigned), stream);
  if (tier1) hipMemsetAsync(cur, 0, (size_t)BT * sizeof(int), stream);

  k1_scores<<<BT / 64, 256, 0, stream>>>(x, gw, scoresT,
                                         tier2 ? xb : nullptr);
  k2a_hist<<<(E * BT) / 1024, 1024, 0, stream>>>(scoresT, hist16);
  k2b_scan<<<E, 256, 0, stream>>>(hist16, thr16);
  k2c_collect<<<E, 1024, 0, stream>>>(scoresT, thr16, o_idx, o_scr, o_cnt,
                                      tier1 ? cur : nullptr,
                                      tier1 ? slt : nullptr);
  if (tier1) {
    k4c_mfma<<<4096, 256, 0, stream>>>(xb, bm, o_idx, o_scr, yD);
    k5g<<<BT / 4, 256, 0, stream>>>(yD, cur, slt, bias, res);
  } else if (tier2) {
    hipMemsetAsync(res, 0, (size_t)BT * J * sizeof(float), stream);
    k4b_mfma<<<dim3(4, 16, E), 256, 0, stream>>>(xb, bm, o_idx, o_scr, res);
    k5_final<<<8192, 256, 0, stream>>>(res, o_cnt, bias);
  }
}